// Round 1
// baseline (1510.494 us; speedup 1.0000x reference)
//
#include <hip/hip_runtime.h>
#include <math.h>

#define V 2
#define NN 100000
#define KK 8
#define DD 128
#define TILE_N 128
#define LOG2PI 1.8378770664093454f
#define LOG_1EM6 -13.815510557964274f

// ws layout (floats):
//  Wt: [V*K][D][D]  value = W[row][d] stored at Wt[(vk*D + d)*D + row]   (transposed for GEMM)
//  b:  [V*K][D]
//  c:  [V*K]
#define WT_OFF 0
#define WT_SIZE (V*KK*DD*DD)
#define B_OFF WT_SIZE
#define B_SIZE (V*KK*DD)
#define C_OFF (B_OFF + B_SIZE)

// out layout (floats): energies [N][V] | weights [N][V] | total_energies | total_penalty
#define OUT_W_OFF (NN*V)
#define OUT_TE (2*NN*V)
#define OUT_TP (2*NN*V + 1)

__global__ void zero_kernel(float* out) {
    int t = threadIdx.x;
    if (t < 2) out[OUT_TE + t] = 0.0f;
}

// One block per (v,k): Cholesky of sigma + 1e-6 I, W = L^{-1}, b = W mu, c_k, penalty.
__global__ __launch_bounds__(128) void prep_kernel(const float* __restrict__ phi,
                                                   const float* __restrict__ mu,
                                                   const float* __restrict__ sigma,
                                                   float* __restrict__ ws,
                                                   float* __restrict__ out) {
    __shared__ float As[DD][DD + 1];
    __shared__ float Ws[DD][DD + 1];
    __shared__ float mulds[DD];
    __shared__ float red[DD];

    const int tid = threadIdx.x;          // 0..127
    const int vk  = blockIdx.x;           // 0..15
    const int v   = vk >> 3;
    const int k   = vk & 7;

    const float* sig = sigma + (size_t)vk * DD * DD;
    for (int i = 0; i < DD; ++i) {
        float x = sig[i * DD + tid];
        if (i == tid) x += 1e-6f;
        As[i][tid] = x;
    }
    mulds[tid] = mu[vk * DD + tid];
    __syncthreads();

    // penalty partial: sum_d 1/(diag + 1e-12)
    red[tid] = 1.0f / (As[tid][tid] + 1e-12f);
    __syncthreads();
    for (int s = 64; s > 0; s >>= 1) {
        if (tid < s) red[tid] += red[tid + s];
        __syncthreads();
    }
    if (tid == 0) atomicAdd(&out[OUT_TP], red[0]);
    __syncthreads();

    // In-place Cholesky (lower). Thread tid owns row tid.
    for (int j = 0; j < DD; ++j) {
        if (tid == 0) As[j][j] = sqrtf(As[j][j]);
        __syncthreads();
        if (tid > j) As[tid][j] /= As[j][j];
        __syncthreads();
        float lij = (tid > j) ? As[tid][j] : 0.0f;
        for (int c = j + 1; c <= tid; ++c)
            As[tid][c] -= lij * As[c][j];
        __syncthreads();
    }

    // logdet = 2 * sum log L_jj  (with det clip at 1e-6)
    red[tid] = 2.0f * logf(As[tid][tid]);
    __syncthreads();
    for (int s = 64; s > 0; s >>= 1) {
        if (tid < s) red[tid] += red[tid + s];
        __syncthreads();
    }
    float logdet_c = fmaxf(red[0], LOG_1EM6);
    __syncthreads();

    // W = L^{-1}; thread j computes column j by forward substitution.
    {
        const int j = tid;
        for (int i = 0; i < j; ++i) Ws[i][j] = 0.0f;   // upper zeros
        Ws[j][j] = 1.0f / As[j][j];
        for (int i = j + 1; i < DD; ++i) {
            float s0 = 0.0f, s1 = 0.0f;
            int p = j;
            for (; p + 1 < i; p += 2) {
                s0 += As[i][p]     * Ws[p][j];
                s1 += As[i][p + 1] * Ws[p + 1][j];
            }
            if (p < i) s0 += As[i][p] * Ws[p][j];
            Ws[i][j] = -(s0 + s1) / As[i][i];
        }
    }
    __syncthreads();

    // b_i = sum_{j<=i} W[i][j] * mu[j]
    {
        float b = 0.0f;
        for (int j2 = 0; j2 <= tid; ++j2) b += Ws[tid][j2] * mulds[j2];
        ws[B_OFF + vk * DD + tid] = b;
    }

    // c_k = log_softmax(phi)[k] - 0.5*logdet - 0.5*D*log(2pi)
    if (tid == 0) {
        const float* ph = phi + v * KK;
        float m = ph[0];
        for (int i = 1; i < KK; ++i) m = fmaxf(m, ph[i]);
        float s = 0.0f;
        for (int i = 0; i < KK; ++i) s += expf(ph[i] - m);
        float logpi = ph[k] - m - logf(s);
        ws[C_OFF + vk] = logpi - 0.5f * logdet_c - 0.5f * (float)DD * LOG2PI;
    }

    // Store W transposed: Wt[(vk*D + d)*D + row] = W[row][d]
    for (int d = 0; d < DD; ++d)
        ws[WT_OFF + ((size_t)vk * DD + d) * DD + tid] = Ws[tid][d];
}

// Main: per block, TILE_N=128 samples; both views; K components staged through LDS.
__global__ __launch_bounds__(256) void energy_kernel(const float* __restrict__ z,
                                                     const float* __restrict__ ws,
                                                     float* __restrict__ out) {
    __shared__ float zt[DD][TILE_N + 4];   // stride 132 (16B aligned rows)
    __shared__ float wl[DD][DD + 4];       // stride 132
    __shared__ float maha[TILE_N][KK + 1]; // stride 9 -> banks spread
    __shared__ float blds[DD];
    __shared__ float clds[V * KK];
    __shared__ float elds[TILE_N][V];
    __shared__ float red[256];

    const int tid = threadIdx.x;
    const int tx = tid & 15;   // 16 column-groups of n
    const int ty = tid >> 4;   // 16 row-groups
    const int n0 = blockIdx.x * TILE_N;

    if (tid < V * KK) clds[tid] = ws[C_OFF + tid];
    float esum = 0.0f;

    for (int v = 0; v < V; ++v) {
        __syncthreads();  // protect maha/zt from previous iteration readers
        // zero maha
        for (int i = tid; i < TILE_N * KK; i += 256)
            maha[i >> 3][i & 7] = 0.0f;
        // stage z tile transposed: zt[d][n]
        {
            const float* zsrc = z + ((size_t)v * NN + n0) * DD;
            for (int it = 0; it < 16; ++it) {
                int f = it * 256 + tid;       // 4096 float4s
                int n = f >> 5;
                int d4 = (f & 31) * 4;
                float4 val;
                if (n0 + n < NN) val = *(const float4*)(zsrc + (size_t)n * DD + d4);
                else             val = make_float4(0.f, 0.f, 0.f, 0.f);
                zt[d4 + 0][n] = val.x;
                zt[d4 + 1][n] = val.y;
                zt[d4 + 2][n] = val.z;
                zt[d4 + 3][n] = val.w;
            }
        }

        for (int k = 0; k < KK; ++k) {
            __syncthreads();  // previous GEMM done before overwriting wl/blds
            // stage W_k: wl[d][row]
            {
                const float* wsrc = ws + WT_OFF + (size_t)(v * KK + k) * DD * DD;
                for (int it = 0; it < 16; ++it) {
                    int f = it * 256 + tid;
                    int d = f >> 5;
                    int r4 = (f & 31) * 4;
                    *(float4*)&wl[d][r4] = *(const float4*)(wsrc + d * DD + r4);
                }
            }
            if (tid < DD) blds[tid] = ws[B_OFF + (v * KK + k) * DD + tid];
            __syncthreads();

            // GEMM: per-thread 8n x 8rows; columns {4tx..4tx+3, 64+4tx..} rows {4ty..,64+4ty..}
            float acc[8][8];
            #pragma unroll
            for (int a = 0; a < 8; ++a)
                #pragma unroll
                for (int b = 0; b < 8; ++b) acc[a][b] = 0.0f;

            #pragma unroll 4
            for (int d = 0; d < DD; ++d) {
                float4 za = *(const float4*)&zt[d][4 * tx];
                float4 zb = *(const float4*)&zt[d][64 + 4 * tx];
                float4 wa = *(const float4*)&wl[d][4 * ty];
                float4 wb = *(const float4*)&wl[d][64 + 4 * ty];
                float zr[8] = {za.x, za.y, za.z, za.w, zb.x, zb.y, zb.z, zb.w};
                float wr[8] = {wa.x, wa.y, wa.z, wa.w, wb.x, wb.y, wb.z, wb.w};
                #pragma unroll
                for (int a = 0; a < 8; ++a)
                    #pragma unroll
                    for (int b = 0; b < 8; ++b)
                        acc[a][b] += zr[a] * wr[b];
            }

            // epilogue: partial maha per n
            float bl[8];
            #pragma unroll
            for (int b = 0; b < 8; ++b) {
                int row = (b < 4) ? 4 * ty + b : 64 + 4 * ty + (b - 4);
                bl[b] = blds[row];
            }
            #pragma unroll
            for (int a = 0; a < 8; ++a) {
                float s = 0.0f;
                #pragma unroll
                for (int b = 0; b < 8; ++b) {
                    float y = acc[a][b] - bl[b];
                    s += y * y;
                }
                int n = (a < 4) ? 4 * tx + a : 64 + 4 * tx + (a - 4);
                atomicAdd(&maha[n][k], s);
            }
        }
        __syncthreads();  // maha complete

        // energies for view v
        if (tid < TILE_N && (n0 + tid) < NN) {
            float lp[KK];
            float m = -1e30f;
            #pragma unroll
            for (int k = 0; k < KK; ++k) {
                lp[k] = -0.5f * maha[tid][k] + clds[v * KK + k];
                m = fmaxf(m, lp[k]);
            }
            float s = 0.0f;
            #pragma unroll
            for (int k = 0; k < KK; ++k) s += expf(lp[k] - m);
            float e = -(m + logf(s));
            elds[tid][v] = e;
            esum += e;
        }
    }
    __syncthreads();

    // weights + output writes
    if (tid < TILE_N && (n0 + tid) < NN) {
        int n = n0 + tid;
        float e0 = elds[tid][0];
        float e1 = elds[tid][1];
        float m = fmaxf(-e0, -e1);
        float x0 = expf(-e0 - m);
        float x1 = expf(-e1 - m);
        float inv = 1.0f / (x0 + x1);
        out[(size_t)n * V + 0] = e0;
        out[(size_t)n * V + 1] = e1;
        out[OUT_W_OFF + (size_t)n * V + 0] = x0 * inv;
        out[OUT_W_OFF + (size_t)n * V + 1] = x1 * inv;
    }

    // total energies
    red[tid] = esum;
    __syncthreads();
    for (int s = 128; s > 0; s >>= 1) {
        if (tid < s) red[tid] += red[tid + s];
        __syncthreads();
    }
    if (tid == 0) atomicAdd(&out[OUT_TE], red[0]);
}

extern "C" void kernel_launch(void* const* d_in, const int* in_sizes, int n_in,
                              void* d_out, int out_size, void* d_ws, size_t ws_size,
                              hipStream_t stream) {
    const float* z     = (const float*)d_in[0];
    const float* phi   = (const float*)d_in[1];
    const float* mu    = (const float*)d_in[2];
    const float* sigma = (const float*)d_in[3];
    float* out = (float*)d_out;
    float* ws  = (float*)d_ws;

    hipLaunchKernelGGL(zero_kernel, dim3(1), dim3(64), 0, stream, out);
    hipLaunchKernelGGL(prep_kernel, dim3(V * KK), dim3(128), 0, stream, phi, mu, sigma, ws, out);
    int nblocks = (NN + TILE_N - 1) / TILE_N;
    hipLaunchKernelGGL(energy_kernel, dim3(nblocks), dim3(256), 0, stream, z, ws, out);
}

// Round 2
// 564.159 us; speedup vs baseline: 2.6774x; 2.6774x over previous
//
#include <hip/hip_runtime.h>
#include <math.h>

#define V 2
#define NN 100000
#define KK 8
#define DD 128
#define TILE_N 128
#define LOG2PI 1.8378770664093454f
#define LOG_1EM6 -13.815510557964274f

// ws layout (bytes):
//  whi: [16][16384] ushort  (swizzled LDS image per (v,k))   @ 0       (512 KB)
//  wlo: [16][16384] ushort                                    @ 524288 (512 KB)
//  b:   [16][128] float                                       @ 1048576 (8 KB)
//  c:   [16] float                                            @ 1056768
#define WLO_B 524288
#define BV_B  1048576
#define C_B   1056768

// out layout (floats): energies [N][V] | weights [N][V] | total_energies | total_penalty
#define OUT_W_OFF (NN*V)
#define OUT_TE (2*NN*V)
#define OUT_TP (2*NN*V + 1)

typedef __attribute__((ext_vector_type(8))) short bf16x8;
typedef __attribute__((ext_vector_type(4))) float f32x4;

__device__ __forceinline__ unsigned short f2bf_rtn(float f) {
    unsigned u = __builtin_bit_cast(unsigned, f);
    unsigned r = u + 0x7FFFu + ((u >> 16) & 1u);
    return (unsigned short)(r >> 16);
}
__device__ __forceinline__ float bf2f(unsigned short h) {
    unsigned u = ((unsigned)h) << 16;
    return __builtin_bit_cast(float, u);
}

__global__ void zero_kernel(float* out) {
    int t = threadIdx.x;
    if (t < 2) out[OUT_TE + t] = 0.0f;
}

// One block of 512 threads per (v,k).
__global__ __launch_bounds__(512) void prep_kernel(const float* __restrict__ phi,
                                                   const float* __restrict__ mu,
                                                   const float* __restrict__ sigma,
                                                   void* __restrict__ wsv,
                                                   float* __restrict__ out) {
    __shared__ float As[DD][DD + 1];
    __shared__ float Ws[DD][DD + 1];
    __shared__ float Ldiag[DD];
    __shared__ float mulds[DD];
    __shared__ float red[DD];

    const int tid = threadIdx.x;          // 0..511
    const int vk  = blockIdx.x;           // 0..15
    const int v   = vk >> 3;
    const int k   = vk & 7;
    const int r   = tid & 127;
    const int h   = tid >> 7;             // 0..3

    const float* sig = sigma + (size_t)vk * DD * DD;
    for (int i = h; i < DD; i += 4) {
        float x = sig[i * DD + r];
        if (i == r) x += 1e-6f;
        As[i][r] = x;
    }
    if (tid < DD) mulds[tid] = mu[vk * DD + tid];
    __syncthreads();

    // penalty: sum_d 1/(diag + 1e-12)
    if (tid < DD) red[tid] = 1.0f / (As[tid][tid] + 1e-12f);
    __syncthreads();
    for (int s = 64; s > 0; s >>= 1) {
        if (tid < s) red[tid] += red[tid + s];
        __syncthreads();
    }
    if (tid == 0) atomicAdd(&out[OUT_TP], red[0]);
    __syncthreads();

    // Right-looking Cholesky, 4-way column split on the update.
    for (int j = 0; j < DD; ++j) {
        float ljj = sqrtf(As[j][j]);
        if (h == 0) {
            if (r > j)       As[r][j] /= ljj;
            else if (r == j) Ldiag[j] = ljj;
        }
        __syncthreads();
        if (r > j) {
            float lrj = As[r][j];
            for (int c = j + 1 + h; c <= r; c += 4)
                As[r][c] -= lrj * As[c][j];
        }
        __syncthreads();
    }

    // logdet = 2 sum log L_jj (clipped at log 1e-6)
    if (tid < DD) red[tid] = 2.0f * logf(Ldiag[tid]);
    __syncthreads();
    for (int s = 64; s > 0; s >>= 1) {
        if (tid < s) red[tid] += red[tid + s];
        __syncthreads();
    }
    float logdet_c = fmaxf(red[0], LOG_1EM6);
    __syncthreads();

    // trsm: W = L^{-1}; 4 lanes (one quad) per column, shfl-combined partial dots.
    {
        const int j = tid >> 2;   // 0..127
        const int q = tid & 3;
        for (int i = q; i < j; i += 4) Ws[i][j] = 0.0f;
        if (q == 0) Ws[j][j] = 1.0f / Ldiag[j];
        for (int i = j + 1; i < DD; ++i) {
            float s = 0.0f;
            for (int p = j + q; p < i; p += 4)
                s += As[i][p] * Ws[p][j];
            s += __shfl_xor(s, 1, 64);
            s += __shfl_xor(s, 2, 64);
            if (q == 0) Ws[i][j] = -s / Ldiag[i];
        }
    }
    __syncthreads();

    // b_i = sum_{j<=i} W[i][j] * mu[j]
    if (tid < DD) {
        float b = 0.0f;
        for (int j2 = 0; j2 <= tid; ++j2) b += Ws[tid][j2] * mulds[j2];
        ((float*)((char*)wsv + BV_B))[vk * DD + tid] = b;
    }

    // c_k = log_softmax(phi)[k] - 0.5*logdet - 0.5*D*log(2pi)
    if (tid == 0) {
        const float* ph = phi + v * KK;
        float m = ph[0];
        for (int i = 1; i < KK; ++i) m = fmaxf(m, ph[i]);
        float s = 0.0f;
        for (int i = 0; i < KK; ++i) s += expf(ph[i] - m);
        float logpi = ph[k] - m - logf(s);
        ((float*)((char*)wsv + C_B))[vk] = logpi - 0.5f * logdet_c - 0.5f * (float)DD * LOG2PI;
    }

    // W -> bf16 hi/lo, XOR-swizzled LDS image: elem (row, d=8g+e) at row*128 + (g^(row&7))*8 + e
    {
        unsigned short* whi = (unsigned short*)wsv + (size_t)vk * 16384;
        unsigned short* wlo = (unsigned short*)((char*)wsv + WLO_B) + (size_t)vk * 16384;
        const int row = tid & 127;
        const int h4  = tid >> 7;
        for (int d = h4 * 32; d < h4 * 32 + 32; ++d) {
            float f = Ws[row][d];
            unsigned short hi = f2bf_rtn(f);
            unsigned short lo = f2bf_rtn(f - bf2f(hi));
            int g = d >> 3, e = d & 7;
            int idx = row * 128 + ((g ^ (row & 7)) << 3) + e;
            whi[idx] = hi;
            wlo[idx] = lo;
        }
    }
}

// Main: block = 128 samples x 128 W-rows; wave tile 32x128; z frags in registers,
// W staged in LDS via global_load_lds (pre-swizzled); split-bf16 3-pass MFMA.
__global__ __launch_bounds__(256, 2) void energy_kernel(const float* __restrict__ z,
                                                        const void* __restrict__ wsv,
                                                        float* __restrict__ out) {
    __shared__ unsigned short wl[32768];     // hi [0..16384) ushorts, lo [16384..32768)
    __shared__ float maha_s[TILE_N][KK + 1];
    __shared__ float bl_s[DD];
    __shared__ float clds[V * KK];
    __shared__ float elds[TILE_N][V];
    __shared__ float red[256];

    const int tid  = threadIdx.x;
    const int lane = tid & 63;
    const int wave = tid >> 6;
    const int quad = lane >> 4;
    const int l16  = lane & 15;
    const int n0   = blockIdx.x * TILE_N;

    const unsigned short* whi_g = (const unsigned short*)wsv;
    const unsigned short* wlo_g = (const unsigned short*)((const char*)wsv + WLO_B);
    const float* b_g = (const float*)((const char*)wsv + BV_B);
    const float* c_g = (const float*)((const char*)wsv + C_B);

    if (tid < V * KK) clds[tid] = c_g[tid];

    float esum = 0.0f;

    for (int v = 0; v < V; ++v) {
        // z fragments -> registers (bf16 hi/lo split)
        bf16x8 zhi[2][4], zlo[2][4];
        #pragma unroll
        for (int mt = 0; mt < 2; ++mt) {
            int n = n0 + wave * 32 + mt * 16 + l16;
            bool ok = (n < NN);
            const float* zp = z + ((size_t)v * NN + n) * DD + quad * 8;
            #pragma unroll
            for (int ds = 0; ds < 4; ++ds) {
                float f[8];
                if (ok) {
                    float4 a  = *(const float4*)(zp + ds * 32);
                    float4 bq = *(const float4*)(zp + ds * 32 + 4);
                    f[0] = a.x;  f[1] = a.y;  f[2] = a.z;  f[3] = a.w;
                    f[4] = bq.x; f[5] = bq.y; f[6] = bq.z; f[7] = bq.w;
                } else {
                    #pragma unroll
                    for (int e = 0; e < 8; ++e) f[e] = 0.0f;
                }
                bf16x8 hi8, lo8;
                #pragma unroll
                for (int e = 0; e < 8; ++e) {
                    unsigned short hu = f2bf_rtn(f[e]);
                    unsigned short lu = f2bf_rtn(f[e] - bf2f(hu));
                    hi8[e] = (short)hu;
                    lo8[e] = (short)lu;
                }
                zhi[mt][ds] = hi8;
                zlo[mt][ds] = lo8;
            }
        }

        for (int k = 0; k < KK; ++k) {
            const int vk = v * KK + k;
            __syncthreads();   // previous compute done; wl free
            // stage W hi+lo (64 KB) flat into LDS
            {
                const char* srch = (const char*)(whi_g + (size_t)vk * 16384);
                const char* srcl = (const char*)(wlo_g + (size_t)vk * 16384);
                char* ldsbase = (char*)wl;
                const int lane_off = wave * 1024 + lane * 16;
                #pragma unroll
                for (int t = 0; t < 8; ++t)
                    __builtin_amdgcn_global_load_lds(
                        (const __attribute__((address_space(1))) void*)(srch + t * 4096 + lane_off),
                        (__attribute__((address_space(3))) void*)(ldsbase + t * 4096 + wave * 1024),
                        16, 0, 0);
                #pragma unroll
                for (int t = 0; t < 8; ++t)
                    __builtin_amdgcn_global_load_lds(
                        (const __attribute__((address_space(1))) void*)(srcl + t * 4096 + lane_off),
                        (__attribute__((address_space(3))) void*)(ldsbase + 32768 + t * 4096 + wave * 1024),
                        16, 0, 0);
            }
            if (tid < DD) bl_s[tid] = b_g[vk * DD + tid];
            __syncthreads();   // drains vmcnt (global_load_lds) + lgkm

            f32x4 acc[2][8];
            #pragma unroll
            for (int mt = 0; mt < 2; ++mt)
                #pragma unroll
                for (int nt = 0; nt < 8; ++nt)
                    acc[mt][nt] = (f32x4)(0.0f);

            #pragma unroll
            for (int ds = 0; ds < 4; ++ds) {
                bf16x8 bh[8], blo[8];
                const int g = ds * 4 + quad;
                #pragma unroll
                for (int nt = 0; nt < 8; ++nt) {
                    int row = nt * 16 + l16;
                    int off = row * 128 + ((g ^ (row & 7)) << 3);
                    bh[nt]  = *(const bf16x8*)&wl[off];
                    blo[nt] = *(const bf16x8*)&wl[16384 + off];
                }
                #pragma unroll
                for (int mt = 0; mt < 2; ++mt)
                    #pragma unroll
                    for (int nt = 0; nt < 8; ++nt) {
                        acc[mt][nt] = __builtin_amdgcn_mfma_f32_16x16x32_bf16(zhi[mt][ds], bh[nt],  acc[mt][nt], 0, 0, 0);
                        acc[mt][nt] = __builtin_amdgcn_mfma_f32_16x16x32_bf16(zhi[mt][ds], blo[nt], acc[mt][nt], 0, 0, 0);
                        acc[mt][nt] = __builtin_amdgcn_mfma_f32_16x16x32_bf16(zlo[mt][ds], bh[nt],  acc[mt][nt], 0, 0, 0);
                    }
            }

            // epilogue: maha[n][k] = sum_rows (y - b)^2 via quad-group shfl reduce
            #pragma unroll
            for (int mt = 0; mt < 2; ++mt) {
                float p[4] = {0.f, 0.f, 0.f, 0.f};
                #pragma unroll
                for (int nt = 0; nt < 8; ++nt) {
                    float bc = bl_s[nt * 16 + l16];
                    f32x4 a = acc[mt][nt];
                    float y0 = a[0] - bc, y1 = a[1] - bc, y2 = a[2] - bc, y3 = a[3] - bc;
                    p[0] += y0 * y0; p[1] += y1 * y1; p[2] += y2 * y2; p[3] += y3 * y3;
                }
                #pragma unroll
                for (int reg = 0; reg < 4; ++reg) {
                    float s = p[reg];
                    s += __shfl_xor(s, 1, 64);
                    s += __shfl_xor(s, 2, 64);
                    s += __shfl_xor(s, 4, 64);
                    s += __shfl_xor(s, 8, 64);
                    if (l16 == 0)
                        maha_s[wave * 32 + mt * 16 + quad * 4 + reg][k] = s;
                }
            }
        }  // k
        __syncthreads();  // maha complete

        if (tid < TILE_N && (n0 + tid) < NN) {
            float lp[KK];
            float m = -1e30f;
            #pragma unroll
            for (int k = 0; k < KK; ++k) {
                lp[k] = -0.5f * maha_s[tid][k] + clds[v * KK + k];
                m = fmaxf(m, lp[k]);
            }
            float s = 0.0f;
            #pragma unroll
            for (int k = 0; k < KK; ++k) s += expf(lp[k] - m);
            float e = -(m + logf(s));
            elds[tid][v] = e;
            esum += e;
        }
    }  // v
    __syncthreads();

    if (tid < TILE_N && (n0 + tid) < NN) {
        int n = n0 + tid;
        float e0 = elds[tid][0];
        float e1 = elds[tid][1];
        float m = fmaxf(-e0, -e1);
        float x0 = expf(-e0 - m);
        float x1 = expf(-e1 - m);
        float inv = 1.0f / (x0 + x1);
        out[(size_t)n * V + 0] = e0;
        out[(size_t)n * V + 1] = e1;
        out[OUT_W_OFF + (size_t)n * V + 0] = x0 * inv;
        out[OUT_W_OFF + (size_t)n * V + 1] = x1 * inv;
    }

    red[tid] = esum;
    __syncthreads();
    for (int s = 128; s > 0; s >>= 1) {
        if (tid < s) red[tid] += red[tid + s];
        __syncthreads();
    }
    if (tid == 0) atomicAdd(&out[OUT_TE], red[0]);
}

extern "C" void kernel_launch(void* const* d_in, const int* in_sizes, int n_in,
                              void* d_out, int out_size, void* d_ws, size_t ws_size,
                              hipStream_t stream) {
    const float* z     = (const float*)d_in[0];
    const float* phi   = (const float*)d_in[1];
    const float* mu    = (const float*)d_in[2];
    const float* sigma = (const float*)d_in[3];
    float* out = (float*)d_out;

    hipLaunchKernelGGL(zero_kernel, dim3(1), dim3(64), 0, stream, out);
    hipLaunchKernelGGL(prep_kernel, dim3(V * KK), dim3(512), 0, stream, phi, mu, sigma, d_ws, out);
    int nblocks = (NN + TILE_N - 1) / TILE_N;
    hipLaunchKernelGGL(energy_kernel, dim3(nblocks), dim3(256), 0, stream, z, d_ws, out);
}

// Round 3
// 465.877 us; speedup vs baseline: 3.2423x; 1.2110x over previous
//
#include <hip/hip_runtime.h>
#include <math.h>

#define V 2
#define NN 100000
#define KK 8
#define DD 128
#define TILE_N 128
#define LOG2PI 1.8378770664093454f
#define LOG_1EM6 -13.815510557964274f

// ws layout (bytes):
//  whi: [16][16384] ushort  (swizzled LDS image per (v,k))   @ 0       (512 KB)
//  wlo: [16][16384] ushort                                    @ 524288 (512 KB)
//  b:   [16][128] float                                       @ 1048576 (8 KB)
//  c:   [16] float                                            @ 1056768
#define WLO_B 524288
#define BV_B  1048576
#define C_B   1056768

// out layout (floats): energies [N][V] | weights [N][V] | total_energies | total_penalty
#define OUT_W_OFF (NN*V)
#define OUT_TE (2*NN*V)
#define OUT_TP (2*NN*V + 1)

typedef __attribute__((ext_vector_type(8))) short bf16x8;
typedef __attribute__((ext_vector_type(4))) float f32x4;

__device__ __forceinline__ unsigned short f2bf_rtn(float f) {
    unsigned u = __builtin_bit_cast(unsigned, f);
    unsigned r = u + 0x7FFFu + ((u >> 16) & 1u);
    return (unsigned short)(r >> 16);
}
__device__ __forceinline__ float bf2f(unsigned short h) {
    unsigned u = ((unsigned)h) << 16;
    return __builtin_bit_cast(float, u);
}

__global__ void zero_kernel(float* out) {
    int t = threadIdx.x;
    if (t < 2) out[OUT_TE + t] = 0.0f;
}

// One block of 256 threads per (v,k).
// Register-tile right-looking Cholesky (1 barrier/column), then 2-thread/column trsm.
__global__ __launch_bounds__(256) void prep_kernel(const float* __restrict__ phi,
                                                   const float* __restrict__ mu,
                                                   const float* __restrict__ sigma,
                                                   void* __restrict__ wsv,
                                                   float* __restrict__ out) {
    __shared__ float Lf[128 * 129];        // L row-major, stride 129 (lower; upper zeroed)
    __shared__ float Wcm[128 * 129];       // W col-major: Wcm[j*129+i] = W[i][j]
    __shared__ float colbuf[2][132];       // published raw column + [128]=diag
    __shared__ float dvec[128];
    __shared__ float mulds[128];
    __shared__ float red[256];

    const int tid = threadIdx.x;           // 0..255
    const int vk  = blockIdx.x;            // 0..15
    const int v   = vk >> 3;
    const int k   = vk & 7;
    const int R   = tid >> 4;              // tile row-block 0..15
    const int C   = tid & 15;              // tile col-block 0..15

    if (tid < DD) mulds[tid] = mu[vk * DD + tid];

    // Load 8x8 register tile of sigma (+1e-6 I), coalesced-ish (C fastest).
    float A[8][8];
    const float* sig = sigma + (size_t)vk * DD * DD;
    float pen = 0.0f;
    #pragma unroll
    for (int a = 0; a < 8; ++a) {
        const float4* p4 = (const float4*)(sig + (size_t)(8 * R + a) * DD + 8 * C);
        float4 x = p4[0], y = p4[1];
        A[a][0] = x.x; A[a][1] = x.y; A[a][2] = x.z; A[a][3] = x.w;
        A[a][4] = y.x; A[a][5] = y.y; A[a][6] = y.z; A[a][7] = y.w;
        if (R == C) A[a][a] += 1e-6f;
    }
    if (R == C) {
        #pragma unroll
        for (int a = 0; a < 8; ++a) pen += 1.0f / (A[a][a] + 1e-12f);
    }

    // Bootstrap: publish raw column 0.
    if (C == 0) {
        #pragma unroll
        for (int a = 0; a < 8; ++a) colbuf[0][8 * R + a] = A[a][0];
        if (R == 0) colbuf[0][128] = A[0][0];
    }
    __syncthreads();

    // 128 phases, one barrier each.
    for (int cb = 0; cb < 16; ++cb) {
        #pragma unroll
        for (int cc = 0; cc < 8; ++cc) {
            const int c = cb * 8 + cc;
            const float* cur = colbuf[cc & 1];
            float* nxt = colbuf[(cc + 1) & 1];

            float d = cur[128];
            if (tid == 0) dvec[c] = d;
            float inv_d = 1.0f / d;

            float cr[8], cw[8];
            #pragma unroll
            for (int a = 0; a < 8; ++a)
                cr[a] = (8 * R + a > c) ? cur[8 * R + a] : 0.0f;
            #pragma unroll
            for (int b = 0; b < 8; ++b)
                cw[b] = ((8 * C + b > c) ? cur[8 * C + b] : 0.0f) * inv_d;

            #pragma unroll
            for (int a = 0; a < 8; ++a)
                #pragma unroll
                for (int b = 0; b < 8; ++b)
                    A[a][b] -= cr[a] * cw[b];

            // publish raw column c+1 (post-update)
            if (c < 127) {
                const int bn = (cc + 1) & 7;
                if (C == ((c + 1) >> 3)) {
                    #pragma unroll
                    for (int a = 0; a < 8; ++a)
                        nxt[8 * R + a] = A[a][bn];
                    if (R == C) nxt[128] = A[bn][bn];
                }
            }
            __syncthreads();
        }
    }

    // Scale columns -> L, write to LDS (upper zeros). Zero-init Wcm.
    {
        float rs[8];
        #pragma unroll
        for (int b = 0; b < 8; ++b) rs[b] = rsqrtf(dvec[8 * C + b]);
        #pragma unroll
        for (int a = 0; a < 8; ++a) {
            int r = 8 * R + a;
            #pragma unroll
            for (int b = 0; b < 8; ++b) {
                int cg = 8 * C + b;
                Lf[r * 129 + cg] = (r >= cg) ? A[a][b] * rs[b] : 0.0f;
            }
        }
        for (int i = tid; i < 128 * 129; i += 256) Wcm[i] = 0.0f;
    }
    __syncthreads();

    // trsm: W = L^{-1}. Column j = tid>>1, parity split over p, shfl combine.
    {
        const int j = tid >> 1;
        const int par = tid & 1;
        if (par == 0) Wcm[j * 129 + j] = 1.0f / Lf[j * 129 + j];
        // wave-ordered: diag writes precede loop reads (same wave: lanes 2j,2j+1 adjacent)
        for (int i = 1; i < DD; ++i) {
            float s = 0.0f;
            #pragma unroll 4
            for (int p = par; p < i; p += 2)
                s += Lf[i * 129 + p] * Wcm[j * 129 + p];
            s += __shfl_xor(s, 1, 64);
            if (par == 0 && i > j)
                Wcm[j * 129 + i] = -s / Lf[i * 129 + i];
        }
    }
    __syncthreads();

    // b_i = sum_j W[i][j] mu[j]
    if (tid < DD) {
        float b = 0.0f;
        for (int j2 = 0; j2 < DD; ++j2)
            b += Wcm[j2 * 129 + tid] * mulds[j2];
        ((float*)((char*)wsv + BV_B))[vk * DD + tid] = b;
    }

    // pack W -> bf16 hi/lo swizzled global image. 2 threads/row.
    {
        unsigned* whi = (unsigned*)((unsigned short*)wsv + (size_t)vk * 16384);
        unsigned* wlo = (unsigned*)((unsigned short*)((char*)wsv + WLO_B) + (size_t)vk * 16384);
        const int r = tid >> 1;
        const int half = (tid & 1) * 64;
        for (int d0 = half; d0 < half + 64; d0 += 2) {
            float f0 = Wcm[d0 * 129 + r];
            float f1 = Wcm[(d0 + 1) * 129 + r];
            unsigned short h0 = f2bf_rtn(f0);
            unsigned short h1 = f2bf_rtn(f1);
            unsigned short l0 = f2bf_rtn(f0 - bf2f(h0));
            unsigned short l1 = f2bf_rtn(f1 - bf2f(h1));
            int g = d0 >> 3, e = d0 & 7;
            int idx = r * 128 + ((g ^ (r & 7)) << 3) + e;   // even
            whi[idx >> 1] = (unsigned)h0 | ((unsigned)h1 << 16);
            wlo[idx >> 1] = (unsigned)l0 | ((unsigned)l1 << 16);
        }
    }

    // penalty reduce
    red[tid] = pen;
    __syncthreads();
    for (int s = 128; s > 0; s >>= 1) {
        if (tid < s) red[tid] += red[tid + s];
        __syncthreads();
    }
    if (tid == 0) atomicAdd(&out[OUT_TP], red[0]);
    __syncthreads();

    // logdet = sum log d_c  (d_c = L_cc^2), clipped at log(1e-6)
    red[tid] = (tid < DD) ? logf(dvec[tid]) : 0.0f;
    __syncthreads();
    for (int s = 128; s > 0; s >>= 1) {
        if (tid < s) red[tid] += red[tid + s];
        __syncthreads();
    }
    if (tid == 0) {
        float logdet_c = fmaxf(red[0], LOG_1EM6);
        const float* ph = phi + v * KK;
        float m = ph[0];
        for (int i = 1; i < KK; ++i) m = fmaxf(m, ph[i]);
        float s = 0.0f;
        for (int i = 0; i < KK; ++i) s += expf(ph[i] - m);
        float logpi = ph[k] - m - logf(s);
        ((float*)((char*)wsv + C_B))[vk] = logpi - 0.5f * logdet_c - 0.5f * (float)DD * LOG2PI;
    }
}

// Main: block = 128 samples x 128 W-rows; wave tile 32x128; z frags in registers,
// W staged in LDS via global_load_lds (pre-swizzled); split-bf16 3-pass MFMA.
// W is lower-triangular: tiles with nt < 2*ds are exactly zero -> skipped (37.5% cut).
__global__ __launch_bounds__(256, 2) void energy_kernel(const float* __restrict__ z,
                                                        const void* __restrict__ wsv,
                                                        float* __restrict__ out) {
    __shared__ unsigned short wl[32768];     // hi [0..16384) ushorts, lo [16384..32768)
    __shared__ float maha_s[TILE_N][KK + 1];
    __shared__ float bl_s[DD];
    __shared__ float clds[V * KK];
    __shared__ float elds[TILE_N][V];
    __shared__ float red[256];

    const int tid  = threadIdx.x;
    const int lane = tid & 63;
    const int wave = tid >> 6;
    const int quad = lane >> 4;
    const int l16  = lane & 15;
    const int n0   = blockIdx.x * TILE_N;

    const unsigned short* whi_g = (const unsigned short*)wsv;
    const unsigned short* wlo_g = (const unsigned short*)((const char*)wsv + WLO_B);
    const float* b_g = (const float*)((const char*)wsv + BV_B);
    const float* c_g = (const float*)((const char*)wsv + C_B);

    if (tid < V * KK) clds[tid] = c_g[tid];

    float esum = 0.0f;

    for (int v = 0; v < V; ++v) {
        // z fragments -> registers (bf16 hi/lo split)
        bf16x8 zhi[2][4], zlo[2][4];
        #pragma unroll
        for (int mt = 0; mt < 2; ++mt) {
            int n = n0 + wave * 32 + mt * 16 + l16;
            bool ok = (n < NN);
            const float* zp = z + ((size_t)v * NN + n) * DD + quad * 8;
            #pragma unroll
            for (int ds = 0; ds < 4; ++ds) {
                float f[8];
                if (ok) {
                    float4 a  = *(const float4*)(zp + ds * 32);
                    float4 bq = *(const float4*)(zp + ds * 32 + 4);
                    f[0] = a.x;  f[1] = a.y;  f[2] = a.z;  f[3] = a.w;
                    f[4] = bq.x; f[5] = bq.y; f[6] = bq.z; f[7] = bq.w;
                } else {
                    #pragma unroll
                    for (int e = 0; e < 8; ++e) f[e] = 0.0f;
                }
                bf16x8 hi8, lo8;
                #pragma unroll
                for (int e = 0; e < 8; ++e) {
                    unsigned short hu = f2bf_rtn(f[e]);
                    unsigned short lu = f2bf_rtn(f[e] - bf2f(hu));
                    hi8[e] = (short)hu;
                    lo8[e] = (short)lu;
                }
                zhi[mt][ds] = hi8;
                zlo[mt][ds] = lo8;
            }
        }

        for (int k = 0; k < KK; ++k) {
            const int vk = v * KK + k;
            __syncthreads();   // previous compute done; wl free
            // stage W hi+lo (64 KB) flat into LDS
            {
                const char* srch = (const char*)(whi_g + (size_t)vk * 16384);
                const char* srcl = (const char*)(wlo_g + (size_t)vk * 16384);
                char* ldsbase = (char*)wl;
                const int lane_off = wave * 1024 + lane * 16;
                #pragma unroll
                for (int t = 0; t < 8; ++t)
                    __builtin_amdgcn_global_load_lds(
                        (const __attribute__((address_space(1))) void*)(srch + t * 4096 + lane_off),
                        (__attribute__((address_space(3))) void*)(ldsbase + t * 4096 + wave * 1024),
                        16, 0, 0);
                #pragma unroll
                for (int t = 0; t < 8; ++t)
                    __builtin_amdgcn_global_load_lds(
                        (const __attribute__((address_space(1))) void*)(srcl + t * 4096 + lane_off),
                        (__attribute__((address_space(3))) void*)(ldsbase + 32768 + t * 4096 + wave * 1024),
                        16, 0, 0);
            }
            if (tid < DD) bl_s[tid] = b_g[vk * DD + tid];
            __syncthreads();   // drains vmcnt (global_load_lds) + lgkm

            f32x4 acc[2][8];
            #pragma unroll
            for (int mt = 0; mt < 2; ++mt)
                #pragma unroll
                for (int nt = 0; nt < 8; ++nt)
                    acc[mt][nt] = (f32x4)(0.0f);

            #pragma unroll
            for (int ds = 0; ds < 4; ++ds) {
                const int g = ds * 4 + quad;
                #pragma unroll
                for (int nt = 0; nt < 8; ++nt) {
                    if (nt < 2 * ds) continue;   // W tile exactly zero (lower-triangular)
                    int row = nt * 16 + l16;
                    int off = row * 128 + ((g ^ (row & 7)) << 3);
                    bf16x8 bh  = *(const bf16x8*)&wl[off];
                    bf16x8 blo = *(const bf16x8*)&wl[16384 + off];
                    #pragma unroll
                    for (int mt = 0; mt < 2; ++mt) {
                        acc[mt][nt] = __builtin_amdgcn_mfma_f32_16x16x32_bf16(zhi[mt][ds], bh,  acc[mt][nt], 0, 0, 0);
                        acc[mt][nt] = __builtin_amdgcn_mfma_f32_16x16x32_bf16(zhi[mt][ds], blo, acc[mt][nt], 0, 0, 0);
                        acc[mt][nt] = __builtin_amdgcn_mfma_f32_16x16x32_bf16(zlo[mt][ds], bh,  acc[mt][nt], 0, 0, 0);
                    }
                }
            }

            // epilogue: maha[n][k] = sum_rows (y - b)^2 via quad-group shfl reduce
            #pragma unroll
            for (int mt = 0; mt < 2; ++mt) {
                float p[4] = {0.f, 0.f, 0.f, 0.f};
                #pragma unroll
                for (int nt = 0; nt < 8; ++nt) {
                    float bc = bl_s[nt * 16 + l16];
                    f32x4 a = acc[mt][nt];
                    float y0 = a[0] - bc, y1 = a[1] - bc, y2 = a[2] - bc, y3 = a[3] - bc;
                    p[0] += y0 * y0; p[1] += y1 * y1; p[2] += y2 * y2; p[3] += y3 * y3;
                }
                #pragma unroll
                for (int reg = 0; reg < 4; ++reg) {
                    float s = p[reg];
                    s += __shfl_xor(s, 1, 64);
                    s += __shfl_xor(s, 2, 64);
                    s += __shfl_xor(s, 4, 64);
                    s += __shfl_xor(s, 8, 64);
                    if (l16 == 0)
                        maha_s[wave * 32 + mt * 16 + quad * 4 + reg][k] = s;
                }
            }
        }  // k
        __syncthreads();  // maha complete

        if (tid < TILE_N && (n0 + tid) < NN) {
            float lp[KK];
            float m = -1e30f;
            #pragma unroll
            for (int k = 0; k < KK; ++k) {
                lp[k] = -0.5f * maha_s[tid][k] + clds[v * KK + k];
                m = fmaxf(m, lp[k]);
            }
            float s = 0.0f;
            #pragma unroll
            for (int k = 0; k < KK; ++k) s += expf(lp[k] - m);
            float e = -(m + logf(s));
            elds[tid][v] = e;
            esum += e;
        }
    }  // v
    __syncthreads();

    if (tid < TILE_N && (n0 + tid) < NN) {
        int n = n0 + tid;
        float e0 = elds[tid][0];
        float e1 = elds[tid][1];
        float m = fmaxf(-e0, -e1);
        float x0 = expf(-e0 - m);
        float x1 = expf(-e1 - m);
        float inv = 1.0f / (x0 + x1);
        out[(size_t)n * V + 0] = e0;
        out[(size_t)n * V + 1] = e1;
        out[OUT_W_OFF + (size_t)n * V + 0] = x0 * inv;
        out[OUT_W_OFF + (size_t)n * V + 1] = x1 * inv;
    }

    red[tid] = esum;
    __syncthreads();
    for (int s = 128; s > 0; s >>= 1) {
        if (tid < s) red[tid] += red[tid + s];
        __syncthreads();
    }
    if (tid == 0) atomicAdd(&out[OUT_TE], red[0]);
}

extern "C" void kernel_launch(void* const* d_in, const int* in_sizes, int n_in,
                              void* d_out, int out_size, void* d_ws, size_t ws_size,
                              hipStream_t stream) {
    const float* z     = (const float*)d_in[0];
    const float* phi   = (const float*)d_in[1];
    const float* mu    = (const float*)d_in[2];
    const float* sigma = (const float*)d_in[3];
    float* out = (float*)d_out;

    hipLaunchKernelGGL(zero_kernel, dim3(1), dim3(64), 0, stream, out);
    hipLaunchKernelGGL(prep_kernel, dim3(V * KK), dim3(256), 0, stream, phi, mu, sigma, d_ws, out);
    int nblocks = (NN + TILE_N - 1) / TILE_N;
    hipLaunchKernelGGL(energy_kernel, dim3(nblocks), dim3(256), 0, stream, z, d_ws, out);
}